// Round 1
// baseline (1012.577 us; speedup 1.0000x reference)
//
#include <hip/hip_runtime.h>

// VQ codebook lookup: x[B=16, D=256, H=32, W=32] fp32, E[D=256, K=8192] fp32.
// N = B*H*W = 16384 tokens. For each token: argmin_k (||E_k||^2 - 2 x.E_k),
// then outputs: out0 = x + (E[:,k*] - x)  (STE, numerically ~= quantized),
//               out1 = E[:,k*], out2 = (float)k*.
// Compute-bound: 2*N*K*D = 68.7 GFLOP fp32 vector -> 437us roofline.

#define D_   256
#define HW_  1024
#define N_   16384
#define K_   8192
#define SPLITS 4
#define KR   (K_ / SPLITS)   // 2048 codes per K-split
#define TM   128             // tokens per block
#define TK   128             // codes per K-tile
#define DT   32              // d-slice staged in LDS
#define NKT  (KR / TK)       // 16 K-tiles per block

#define OUT1_OFF 4194304     // B*D*H*W
#define IND_OFF  8388608     // 2*B*D*H*W

// ---------------- kernel A: codebook column norms ----------------
__global__ __launch_bounds__(256)
void cnorm_kernel(const float* __restrict__ E, float* __restrict__ c) {
    int k = blockIdx.x * 256 + threadIdx.x;
    float s = 0.f;
    for (int d = 0; d < D_; ++d) {
        float v = E[(size_t)d * K_ + k];
        s = fmaf(v, v, s);
    }
    c[k] = s;
}

// ---------------- kernel B: fused distance GEMM + argmin ----------------
// grid (N/TM, SPLITS), block 256. Thread (ty=tid>>4, tx=tid&15) owns an
// 8x8 (token x code) fp32 accumulator micro-tile.
__global__ __launch_bounds__(256, 2)
void argmin_kernel(const float* __restrict__ x, const float* __restrict__ E,
                   const float* __restrict__ c,
                   float* __restrict__ pd, int* __restrict__ pi) {
    __shared__ float xs[DT][TM];        // 16 KB
    __shared__ float es[DT][TK];        // 16 KB
    __shared__ float red_d[TM][16];     // 8 KB
    __shared__ int   red_i[TM][16];     // 8 KB

    const int tid = threadIdx.x;
    const int tx  = tid & 15;
    const int ty  = tid >> 4;

    const int n0 = blockIdx.x * TM;          // token tile base
    const int split = blockIdx.y;
    const int b  = n0 >> 10;                 // HW_ = 1024 tokens per batch
    const int s0 = n0 & 1023;
    const float* xbase = x + (size_t)b * D_ * HW_ + s0;

    float bestd = 3.4e38f;                   // running best (threads tid<TM only)
    int   besti = 0;

    for (int kt = 0; kt < NKT; ++kt) {
        const int kbase = split * KR + kt * TK;

        float acc[8][8];
        #pragma unroll
        for (int i = 0; i < 8; ++i)
            #pragma unroll
            for (int j = 0; j < 8; ++j) acc[i][j] = 0.f;

        for (int db = 0; db < D_ / DT; ++db) {
            __syncthreads();   // protect LDS tiles from previous iteration readers
            // stage x-slice [DT x TM]: rows contiguous along spatial dim (coalesced)
            {
                const float* gx = xbase + (size_t)(db * DT) * HW_;
                const float* ge = E + (size_t)(db * DT) * K_ + kbase;
                #pragma unroll
                for (int j = 0; j < 4; ++j) {
                    int v  = tid + 256 * j;      // 0..1023 vec4 slots
                    int dd = v >> 5;
                    int tv = v & 31;
                    float4 t = *(const float4*)(gx + (size_t)dd * HW_ + tv * 4);
                    *(float4*)&xs[dd][tv * 4] = t;
                    float4 u = *(const float4*)(ge + (size_t)dd * K_ + tv * 4);
                    *(float4*)&es[dd][tv * 4] = u;
                }
            }
            __syncthreads();

            #pragma unroll 4
            for (int dd = 0; dd < DT; ++dd) {
                float4 xv0 = *(const float4*)&xs[dd][ty * 8];
                float4 xv1 = *(const float4*)&xs[dd][ty * 8 + 4];
                float4 ev0 = *(const float4*)&es[dd][tx * 8];
                float4 ev1 = *(const float4*)&es[dd][tx * 8 + 4];
                float ax[8] = {xv0.x, xv0.y, xv0.z, xv0.w, xv1.x, xv1.y, xv1.z, xv1.w};
                float ae[8] = {ev0.x, ev0.y, ev0.z, ev0.w, ev1.x, ev1.y, ev1.z, ev1.w};
                #pragma unroll
                for (int i = 0; i < 8; ++i)
                    #pragma unroll
                    for (int j = 0; j < 8; ++j)
                        acc[i][j] = fmaf(ax[i], ae[j], acc[i][j]);
            }
        }

        // per-thread argmin over its 8 codes for each of its 8 tokens
        float cv[8];
        #pragma unroll
        for (int j = 0; j < 8; ++j) cv[j] = c[kbase + tx * 8 + j];
        #pragma unroll
        for (int i = 0; i < 8; ++i) {
            float md = 3.4e38f; int mi = 0;
            #pragma unroll
            for (int j = 0; j < 8; ++j) {
                float dv = fmaf(-2.f, acc[i][j], cv[j]);
                if (dv < md) { md = dv; mi = kbase + tx * 8 + j; }  // strict <: first-min
            }
            red_d[ty * 8 + i][tx] = md;
            red_i[ty * 8 + i][tx] = mi;
        }
        __syncthreads();
        if (tid < TM) {
            #pragma unroll
            for (int xx = 0; xx < 16; ++xx) {   // ascending tx = ascending k
                float dv = red_d[tid][xx];
                if (dv < bestd) { bestd = dv; besti = red_i[tid][xx]; }
            }
        }
        // red_* not rewritten until after next kt's db-loop syncs -> safe
    }

    if (tid < TM) {
        int n = n0 + tid;
        pd[split * N_ + n] = bestd;
        pi[split * N_ + n] = besti;
    }
}

// ---------------- kernel C: merge K-splits + gather + write outputs ----------------
// grid N/64, block 256. 64 tokens per block; writes coalesced along spatial dim.
__global__ __launch_bounds__(256)
void write_kernel(const float* __restrict__ x, const float* __restrict__ E,
                  const float* __restrict__ pd, const int* __restrict__ pi,
                  float* __restrict__ out) {
    __shared__ int kst[64];
    const int n0 = blockIdx.x * 64;
    const int b  = n0 >> 10;
    const int s0 = n0 & 1023;
    const int tid = threadIdx.x;

    if (tid < 64) {
        int n = n0 + tid;
        float bd = 3.4e38f; int bi = 0;
        #pragma unroll
        for (int sp = 0; sp < SPLITS; ++sp) {   // ascending split = ascending k
            float dv = pd[sp * N_ + n];
            int   iv = pi[sp * N_ + n];
            if (dv < bd) { bd = dv; bi = iv; }
        }
        kst[tid] = bi;
        out[IND_OFF + n] = (float)bi;           // index emitted as float32 (exact)
    }
    __syncthreads();

    const int lane = tid & 63;
    const int dq   = tid >> 6;                  // 4 d-streams
    const int kk   = kst[lane];
    const float* xb = x + (size_t)b * D_ * HW_ + s0 + lane;
    float* o0 = out + (size_t)b * D_ * HW_ + s0 + lane;
    float* o1 = o0 + OUT1_OFF;
    for (int d = dq; d < D_; d += 4) {
        float q  = E[(size_t)d * K_ + kk];      // gather (L2/L3-resident, 8 MB)
        float xv = xb[(size_t)d * HW_];
        float qmx = q - xv;                     // replicate jnp's fp32 rounding
        o0[(size_t)d * HW_] = xv + qmx;         // quantized_x_d (STE)
        o1[(size_t)d * HW_] = q;                // quantized_x
    }
}

extern "C" void kernel_launch(void* const* d_in, const int* in_sizes, int n_in,
                              void* d_out, int out_size, void* d_ws, size_t ws_size,
                              hipStream_t stream) {
    const float* x = (const float*)d_in[0];
    const float* E = (const float*)d_in[1];
    float* out = (float*)d_out;

    float* c  = (float*)d_ws;                  // 8192 f
    float* pd = c + K_;                        // SPLITS*N f
    int*   pi = (int*)(pd + SPLITS * N_);      // SPLITS*N i   (total ~544 KB)

    cnorm_kernel<<<K_ / 256, 256, 0, stream>>>(E, c);
    argmin_kernel<<<dim3(N_ / TM, SPLITS), 256, 0, stream>>>(x, E, c, pd, pi);
    write_kernel<<<N_ / 64, 256, 0, stream>>>(x, E, pd, pi, out);
}

// Round 2
// 1010.914 us; speedup vs baseline: 1.0016x; 1.0016x over previous
//
#include <hip/hip_runtime.h>

// VQ codebook lookup: x[B=16, D=256, H=32, W=32] fp32, E[D=256, K=8192] fp32.
// N = 16384 tokens. argmin_k (||E_k||^2 - 2 x.E_k) per token, then
// out0 = x + (E[:,k*] - x), out1 = E[:,k*], out2 = (float)k*.
// Compute-bound: 68.7 GFLOP fp32 vector -> 437us floor at 157.3 TF.
// R2: 8x16 micro-tile (LDS bytes/FLOP 0.5->0.375), conflict-free quad-strided
// fragment layout (2-way max = free per m136), argmin hoisted out of kt loop.

#define D_   256
#define HW_  1024
#define N_   16384
#define K_   8192
#define SPLITS 4
#define KR   (K_ / SPLITS)   // 2048 codes per K-split
#define TM   128             // tokens per block
#define TKB  256             // codes per block tile
#define DT   32              // d-slice staged in LDS
#define NKT  (KR / TKB)      // 8 K-tiles per block

#define OUT1_OFF 4194304     // B*D*H*W
#define IND_OFF  8388608     // 2*B*D*H*W

// ---------------- kernel A: codebook column norms ----------------
__global__ __launch_bounds__(256)
void cnorm_kernel(const float* __restrict__ E, float* __restrict__ c) {
    int k = blockIdx.x * 256 + threadIdx.x;
    float s = 0.f;
    for (int d = 0; d < D_; ++d) {
        float v = E[(size_t)d * K_ + k];
        s = fmaf(v, v, s);
    }
    c[k] = s;
}

// ---------------- kernel B: fused distance GEMM + argmin ----------------
// grid (N/TM, SPLITS), block 256 = 16(tx: code groups) x 16(ty: token groups).
// Thread micro-tile: 8 tokens {r*64+ty*4+i} x 16 codes {q*64+tx*4+j}.
// All LDS read patterns are <=2-way bank-aliased (free).
__global__ __launch_bounds__(256, 2)
void argmin_kernel(const float* __restrict__ x, const float* __restrict__ E,
                   const float* __restrict__ c,
                   float* __restrict__ pd, int* __restrict__ pi) {
    __shared__ float xs[DT][TM];        // 16 KB
    __shared__ float es[DT][TKB];       // 32 KB (reused for final reduction)

    const int tid = threadIdx.x;
    const int tx  = tid & 15;
    const int ty  = tid >> 4;

    const int n0 = blockIdx.x * TM;          // token tile base
    const int split = blockIdx.y;
    const int b  = n0 >> 10;                 // HW_ = 1024 tokens per batch
    const int s0 = n0 & 1023;
    const float* xbase = x + (size_t)b * D_ * HW_ + s0;

    float bestd[8];
    int   besti[8];
    #pragma unroll
    for (int i = 0; i < 8; ++i) { bestd[i] = 3.4e38f; besti[i] = 0x7fffffff; }

    for (int kt = 0; kt < NKT; ++kt) {
        const int kbase = split * KR + kt * TKB;

        float acc[8][16];
        #pragma unroll
        for (int i = 0; i < 8; ++i)
            #pragma unroll
            for (int j = 0; j < 16; ++j) acc[i][j] = 0.f;

        for (int db = 0; db < D_ / DT; ++db) {
            __syncthreads();   // protect LDS tiles from previous readers
            const float* gx = xbase + (size_t)(db * DT) * HW_;
            const float* ge = E + (size_t)(db * DT) * K_ + kbase;
            // stage xs [DT x TM]: 1024 float4 slots, coalesced along spatial dim
            #pragma unroll
            for (int j = 0; j < 4; ++j) {
                int v  = tid + 256 * j;
                int dd = v >> 5;
                int tv = v & 31;
                *(float4*)&xs[dd][tv * 4] = *(const float4*)(gx + (size_t)dd * HW_ + tv * 4);
            }
            // stage es [DT x TKB]: 2048 float4 slots, coalesced along K
            #pragma unroll
            for (int j = 0; j < 8; ++j) {
                int v  = tid + 256 * j;
                int dd = v >> 6;
                int c4 = v & 63;
                *(float4*)&es[dd][c4 * 4] = *(const float4*)(ge + (size_t)dd * K_ + c4 * 4);
            }
            __syncthreads();

            #pragma unroll 2
            for (int dd = 0; dd < DT; ++dd) {
                float4 xv0 = *(const float4*)&xs[dd][ty * 4];          // tokens ty*4+i
                float4 xv1 = *(const float4*)&xs[dd][64 + ty * 4];     // tokens 64+ty*4+i
                float4 e0  = *(const float4*)&es[dd][tx * 4];          // codes tx*4+j
                float4 e1  = *(const float4*)&es[dd][64 + tx * 4];
                float4 e2  = *(const float4*)&es[dd][128 + tx * 4];
                float4 e3  = *(const float4*)&es[dd][192 + tx * 4];
                float ax[8]  = {xv0.x, xv0.y, xv0.z, xv0.w, xv1.x, xv1.y, xv1.z, xv1.w};
                float ae[16] = {e0.x, e0.y, e0.z, e0.w, e1.x, e1.y, e1.z, e1.w,
                                e2.x, e2.y, e2.z, e2.w, e3.x, e3.y, e3.z, e3.w};
                #pragma unroll
                for (int i = 0; i < 8; ++i)
                    #pragma unroll
                    for (int j = 0; j < 16; ++j)
                        acc[i][j] = fmaf(ax[i], ae[j], acc[i][j]);
            }
        }

        // fold this K-tile into per-thread running argmin.
        // Scan order within thread is ascending k (kt asc, q asc, jj asc),
        // so strict < keeps the first (lowest-k) minimum.
        #pragma unroll
        for (int q = 0; q < 4; ++q) {
            float4 cq = *(const float4*)&c[kbase + q * 64 + tx * 4];
            float cv[4] = {cq.x, cq.y, cq.z, cq.w};
            #pragma unroll
            for (int jj = 0; jj < 4; ++jj) {
                int k = kbase + q * 64 + tx * 4 + jj;
                #pragma unroll
                for (int i = 0; i < 8; ++i) {
                    float dv = fmaf(-2.f, acc[i][q * 4 + jj], cv[jj]);
                    if (dv < bestd[i]) { bestd[i] = dv; besti[i] = k; }
                }
            }
        }
    }

    // final cross-tx reduction (reuse es/xs as scratch).
    // Threads hold interleaved k-ranges -> ties must pick lower index.
    __syncthreads();
    float (*red_d)[16] = (float(*)[16])es;   // 128x16 floats = 8 KB
    int   (*red_i)[16] = (int  (*)[16])xs;   // 8 KB
    #pragma unroll
    for (int i = 0; i < 8; ++i) {
        int t = (i >> 2) * 64 + ty * 4 + (i & 3);
        red_d[t][tx] = bestd[i];
        red_i[t][tx] = besti[i];
    }
    __syncthreads();
    if (tid < TM) {
        float bd = 3.4e38f; int bi = 0x7fffffff;
        #pragma unroll
        for (int xx = 0; xx < 16; ++xx) {
            float dv = red_d[tid][xx];
            int   iv = red_i[tid][xx];
            if (dv < bd || (dv == bd && iv < bi)) { bd = dv; bi = iv; }
        }
        int n = n0 + tid;
        pd[split * N_ + n] = bd;
        pi[split * N_ + n] = bi;
    }
}

// ---------------- kernel C: merge K-splits + gather + write outputs ----------------
// grid N/64, block 256. 64 tokens per block; writes coalesced along spatial dim.
__global__ __launch_bounds__(256)
void write_kernel(const float* __restrict__ x, const float* __restrict__ E,
                  const float* __restrict__ pd, const int* __restrict__ pi,
                  float* __restrict__ out) {
    __shared__ int kst[64];
    const int n0 = blockIdx.x * 64;
    const int b  = n0 >> 10;
    const int s0 = n0 & 1023;
    const int tid = threadIdx.x;

    if (tid < 64) {
        int n = n0 + tid;
        float bd = 3.4e38f; int bi = 0;
        #pragma unroll
        for (int sp = 0; sp < SPLITS; ++sp) {   // ascending split = ascending k
            float dv = pd[sp * N_ + n];
            int   iv = pi[sp * N_ + n];
            if (dv < bd) { bd = dv; bi = iv; }  // strict <: splits partition k ascending
        }
        kst[tid] = bi;
        out[IND_OFF + n] = (float)bi;           // index emitted as float32 (exact)
    }
    __syncthreads();

    const int lane = tid & 63;
    const int dq   = tid >> 6;                  // 4 d-streams
    const int kk   = kst[lane];
    const float* xb = x + (size_t)b * D_ * HW_ + s0 + lane;
    float* o0 = out + (size_t)b * D_ * HW_ + s0 + lane;
    float* o1 = o0 + OUT1_OFF;
    for (int d = dq; d < D_; d += 4) {
        float q  = E[(size_t)d * K_ + kk];      // gather (L2/L3-resident, 8 MB)
        float xv = xb[(size_t)d * HW_];
        float qmx = q - xv;                     // replicate jnp's fp32 rounding
        o0[(size_t)d * HW_] = xv + qmx;         // quantized_x_d (STE)
        o1[(size_t)d * HW_] = q;                // quantized_x
    }
}

extern "C" void kernel_launch(void* const* d_in, const int* in_sizes, int n_in,
                              void* d_out, int out_size, void* d_ws, size_t ws_size,
                              hipStream_t stream) {
    const float* x = (const float*)d_in[0];
    const float* E = (const float*)d_in[1];
    float* out = (float*)d_out;

    float* c  = (float*)d_ws;                  // 8192 f
    float* pd = c + K_;                        // SPLITS*N f
    int*   pi = (int*)(pd + SPLITS * N_);      // SPLITS*N i   (total ~544 KB)

    cnorm_kernel<<<K_ / 256, 256, 0, stream>>>(E, c);
    argmin_kernel<<<dim3(N_ / TM, SPLITS), 256, 0, stream>>>(x, E, c, pd, pi);
    write_kernel<<<N_ / 64, 256, 0, stream>>>(x, E, pd, pi, out);
}